// Round 6
// baseline (1538.041 us; speedup 1.0000x reference)
//
#include <hip/hip_runtime.h>
#include <hip/hip_bf16.h>
#include <math.h>

// B=16384, NB=8, NA=16, D=128, IN_DIM=2304, QK_DIM=384, V_DIM=128
static constexpr size_t OFF_ATT = 262144;      // attended_sf (33,554,432 f32)
static constexpr size_t OFF_LOG = 33816576;    // attn_logits
static constexpr size_t OFF_W   = 33947648;    // attention_weights
static constexpr size_t OFF_KM  = 34078720;    // keys_masked
static constexpr size_t OFF_VM  = 84410368;    // values_masked (268,435,456 f32)
static constexpr size_t OFF_SIM = 352845824;   // sim (7)

typedef short bf16x8 __attribute__((ext_vector_type(8)));
typedef float f32x4 __attribute__((ext_vector_type(4)));

__device__ inline unsigned short f2bf(float f) {
  union { float f; unsigned u; } x; x.f = f;
  unsigned r = x.u + 0x7FFFu + ((x.u >> 16) & 1u);  // RNE
  return (unsigned short)(r >> 16);
}

__device__ inline float wave_sum(float v) {
#pragma unroll
  for (int o = 32; o > 0; o >>= 1) v += __shfl_xor(v, o, 64);
  return v;
}

// One wave per (b,n) row: inverse L2 norm of task rows. Also zero sim slots.
__global__ void norm_kernel(const float* __restrict__ task, float* __restrict__ invn,
                            float* __restrict__ simo) {
  int idx = blockIdx.x * 4 + (threadIdx.x >> 6);
  int lane = threadIdx.x & 63;
  float t0 = task[(size_t)idx * 128 + lane];
  float t1 = task[(size_t)idx * 128 + 64 + lane];
  float s = wave_sum(t0 * t0 + t1 * t1);
  if (lane == 0) invn[idx] = rsqrtf(s);
  if (blockIdx.x == 0 && threadIdx.x < 7) simo[threadIdx.x] = 0.0f;
}

// Tiled transpose+cvt: WT[n][k] = bf16(W[k][n]). 64x64 tiles, coalesced both sides.
__global__ void wprep_t(const float* __restrict__ W, unsigned short* __restrict__ WT,
                        int K, int N) {
  int ntn = N >> 6;
  int kt = blockIdx.x / ntn, nt = blockIdx.x % ntn;
  int k0 = kt * 64, n0 = nt * 64;
  __shared__ float t[64][65];
  int tid = threadIdx.x;
  int r = tid >> 2, c0 = (tid & 3) * 16;
#pragma unroll
  for (int q = 0; q < 4; ++q) {
    float4 v = *(const float4*)(W + (size_t)(k0 + r) * N + n0 + c0 + q * 4);
    t[r][c0 + q * 4 + 0] = v.x; t[r][c0 + q * 4 + 1] = v.y;
    t[r][c0 + q * 4 + 2] = v.z; t[r][c0 + q * 4 + 3] = v.w;
  }
  __syncthreads();
  int n = tid >> 2, kc0 = (tid & 3) * 16;
#pragma unroll
  for (int q = 0; q < 4; ++q) {
    int kc = kc0 + q * 4;
    ushort4 o = make_ushort4(f2bf(t[kc + 0][n]), f2bf(t[kc + 1][n]),
                             f2bf(t[kc + 2][n]), f2bf(t[kc + 3][n]));
    *(ushort4*)(WT + (size_t)(n0 + n) * K + k0 + kc) = o;
  }
}

// Fused MFMA GEMM building A = [basis|sf|task*invn] on the fly from f32 inputs.
// MODE 0: keys (M=131072 rows), +bias, *mask_rep, fused sim (nt==0 blocks).
// MODE 1: query (M=16384, underlying rows stride 8).
// 128x128 tile, BK=32, 4 waves. A: reg-staged f32->bf16, LDS pitch 40 (padded).
// B: global_load_lds 16B into linear [128][32], both double-buffered.
// Thread-pair staging: thread owns rows 2p,2p+1 (+redundant row 2p+2 load) so
// all consecutive-row sim diffs are thread-local (no shuffles).
template <int MODE>
__global__ __launch_bounds__(256) void qk_gemm_fused(
    const float* __restrict__ basis, const float* __restrict__ sf,
    const float* __restrict__ task, const float* __restrict__ invn,
    const unsigned short* __restrict__ WT, const float* __restrict__ bias,
    const float* __restrict__ mask, float* __restrict__ outp,
    float* __restrict__ simo) {
  __shared__ unsigned short As[2 * 5120];  // [2][128][40] bf16
  __shared__ unsigned short Bs[2 * 4096];  // [2][128][32] bf16 (gload_lds linear)
  int nwg = gridDim.x, per = nwg >> 3;
  int bid = blockIdx.x;
  int swz = (bid & 7) * per + (bid >> 3);
  int mt = swz / 3, nt = swz - mt * 3;
  int tid = threadIdx.x;
  int wave = tid >> 6, lane = tid & 63;
  int wr = wave >> 1, wc = wave & 1;
  int m0g = mt * 128, n0g = nt * 128;
  int la = lane & 15, lk = (lane >> 4) * 8;

  // B staging geometry: chunk c = wave*128 + lane (+64); row=c>>2, kc=(c&3)*8
  int c_lo = wave * 128 + lane;
  int brow0 = c_lo >> 2, bkc0 = (c_lo & 3) * 8;
  int c_hi = c_lo + 64;
  int brow1 = c_hi >> 2, bkc1 = (c_hi & 3) * 8;
  const unsigned short* bg0 = WT + (size_t)(n0g + brow0) * 2304 + bkc0;
  const unsigned short* bg1 = WT + (size_t)(n0g + brow1) * 2304 + bkc1;
  int ldsB0 = wave * 1024;  // elements; wave-uniform (HW adds lane*16B)
  int ldsB1 = ldsB0 + 512;

  // A staging geometry
  int p = tid & 63, part = tid >> 6;
  int r0 = 2 * p, r1 = r0 + 1;
  constexpr bool SIM = (MODE == 0);
  bool do_sim = SIM && (nt == 0);
  bool has_odd = do_sim && ((p & 3) != 3);  // pair (2p+1,2p+2); skips n==7 and p==63
  size_t R0 = (MODE == 1) ? (size_t)(m0g + r0) * 8 : (size_t)(m0g + r0);
  size_t R1 = (MODE == 1) ? (size_t)(m0g + r1) * 8 : (size_t)(m0g + r1);
  size_t R2 = has_odd ? (size_t)(m0g + r0 + 2) : R1;
  float iv0 = invn[R0], iv1 = invn[R1], iv2 = invn[R2];
  int kofs = part * 8;

  float4 a00 = {0,0,0,0}, a01 = {0,0,0,0}, a10 = {0,0,0,0}, a11 = {0,0,0,0};
  float4 a20 = {0,0,0,0}, a21 = {0,0,0,0};
  float sa = 0.f, sb = 0.f;

  auto LOADA = [&](int k0) {
    const float *q0, *q1, *q2;
    bool sc = false;
    if (k0 < 128) {
      q0 = basis + R0 * 128 + k0 + kofs;
      q1 = basis + R1 * 128 + k0 + kofs;
      q2 = basis + R2 * 128 + k0 + kofs;
    } else if (k0 < 2176) {
      int kk = k0 - 128 + kofs;
      q0 = sf + R0 * 2048 + kk;
      q1 = sf + R1 * 2048 + kk;
      q2 = sf + R2 * 2048 + kk;
    } else {
      int kk = k0 - 2176 + kofs;
      q0 = task + R0 * 128 + kk;
      q1 = task + R1 * 128 + kk;
      q2 = task + R2 * 128 + kk;
      sc = true;
    }
    a00 = *(const float4*)q0; a01 = *(const float4*)(q0 + 4);
    a10 = *(const float4*)q1; a11 = *(const float4*)(q1 + 4);
    if (has_odd) { a20 = *(const float4*)q2; a21 = *(const float4*)(q2 + 4); }
    if (sc) {
      a00.x *= iv0; a00.y *= iv0; a00.z *= iv0; a00.w *= iv0;
      a01.x *= iv0; a01.y *= iv0; a01.z *= iv0; a01.w *= iv0;
      a10.x *= iv1; a10.y *= iv1; a10.z *= iv1; a10.w *= iv1;
      a11.x *= iv1; a11.y *= iv1; a11.z *= iv1; a11.w *= iv1;
      if (has_odd) {
        a20.x *= iv2; a20.y *= iv2; a20.z *= iv2; a20.w *= iv2;
        a21.x *= iv2; a21.y *= iv2; a21.z *= iv2; a21.w *= iv2;
      }
    }
  };

  auto SIMACC = [&]() {
    if (!do_sim) return;
    float d;
    d = a00.x - a10.x; sa = fmaf(d, d, sa);
    d = a00.y - a10.y; sa = fmaf(d, d, sa);
    d = a00.z - a10.z; sa = fmaf(d, d, sa);
    d = a00.w - a10.w; sa = fmaf(d, d, sa);
    d = a01.x - a11.x; sa = fmaf(d, d, sa);
    d = a01.y - a11.y; sa = fmaf(d, d, sa);
    d = a01.z - a11.z; sa = fmaf(d, d, sa);
    d = a01.w - a11.w; sa = fmaf(d, d, sa);
    if (has_odd) {
      d = a10.x - a20.x; sb = fmaf(d, d, sb);
      d = a10.y - a20.y; sb = fmaf(d, d, sb);
      d = a10.z - a20.z; sb = fmaf(d, d, sb);
      d = a10.w - a20.w; sb = fmaf(d, d, sb);
      d = a11.x - a21.x; sb = fmaf(d, d, sb);
      d = a11.y - a21.y; sb = fmaf(d, d, sb);
      d = a11.z - a21.z; sb = fmaf(d, d, sb);
      d = a11.w - a21.w; sb = fmaf(d, d, sb);
    }
  };

  auto CVTW = [&](int cb) {
    unsigned short* aL = As + cb * 5120;
    bf16x8 u = { (short)f2bf(a00.x), (short)f2bf(a00.y), (short)f2bf(a00.z), (short)f2bf(a00.w),
                 (short)f2bf(a01.x), (short)f2bf(a01.y), (short)f2bf(a01.z), (short)f2bf(a01.w) };
    bf16x8 v = { (short)f2bf(a10.x), (short)f2bf(a10.y), (short)f2bf(a10.z), (short)f2bf(a10.w),
                 (short)f2bf(a11.x), (short)f2bf(a11.y), (short)f2bf(a11.z), (short)f2bf(a11.w) };
    *(bf16x8*)(aL + r0 * 40 + kofs) = u;
    *(bf16x8*)(aL + r1 * 40 + kofs) = v;
  };

#define STAGE_B(ks, cb)                                                        \
  do {                                                                         \
    __builtin_amdgcn_global_load_lds(                                          \
        (const __attribute__((address_space(1))) void*)(bg0 + (ks) * 32),      \
        (__attribute__((address_space(3))) void*)(Bs + (cb) * 4096 + ldsB0),   \
        16, 0, 0);                                                             \
    __builtin_amdgcn_global_load_lds(                                          \
        (const __attribute__((address_space(1))) void*)(bg1 + (ks) * 32),      \
        (__attribute__((address_space(3))) void*)(Bs + (cb) * 4096 + ldsB1),   \
        16, 0, 0);                                                             \
  } while (0)

  f32x4 acc[4][4];
#pragma unroll
  for (int i = 0; i < 4; ++i)
#pragma unroll
    for (int j = 0; j < 4; ++j) acc[i][j] = (f32x4)(0.f);

  // prologue: tile 0
  LOADA(0);
  STAGE_B(0, 0);
  SIMACC();
  CVTW(0);
  __syncthreads();

  int cur = 0;
  for (int ks = 0; ks < 72; ++ks) {
    if (ks < 71) {
      LOADA((ks + 1) * 32);        // issue global f32 loads (wait deferred)
      STAGE_B(ks + 1, cur ^ 1);    // async B into next buffer
    }
    {
      const unsigned short* aL = As + cur * 5120;
      const unsigned short* bL = Bs + cur * 4096;
      bf16x8 af[4], bfr[4];
#pragma unroll
      for (int mi = 0; mi < 4; ++mi)
        af[mi] = *(const bf16x8*)(aL + (wr * 64 + mi * 16 + la) * 40 + lk);
#pragma unroll
      for (int ni = 0; ni < 4; ++ni)
        bfr[ni] = *(const bf16x8*)(bL + (wc * 64 + ni * 16 + la) * 32 + lk);
#pragma unroll
      for (int mi = 0; mi < 4; ++mi)
#pragma unroll
        for (int ni = 0; ni < 4; ++ni)
          acc[mi][ni] = __builtin_amdgcn_mfma_f32_16x16x32_bf16(af[mi], bfr[ni], acc[mi][ni], 0, 0, 0);
    }
    if (ks < 71) {
      SIMACC();                    // waits on the f32 loads (after MFMA issued)
      CVTW(cur ^ 1);
    }
    __syncthreads();
    cur ^= 1;
  }
#undef STAGE_B

  // C epilogue
  int rq = lane >> 4;
#pragma unroll
  for (int mi = 0; mi < 4; ++mi) {
#pragma unroll
    for (int ni = 0; ni < 4; ++ni) {
      int colg = nt * 128 + wc * 64 + ni * 16 + la;
#pragma unroll
      for (int j = 0; j < 4; ++j) {
        int rowg = mt * 128 + wr * 64 + mi * 16 + rq * 4 + j;
        float v = acc[mi][ni][j];
        if (MODE == 0)
          v = (v + bias[colg]) * mask[(size_t)rowg * 128 + (unsigned)colg / 3u];
        outp[(size_t)rowg * 384 + colg] = v;
      }
    }
  }

  // sim epilogue: reduce the 4 k-parts per row pair, then atomicAdd (nt==0 only)
  if (SIM) {
    if (do_sim) {
      float* sred = (float*)Bs;  // 512 f32 = 2KB, Bs dead after final barrier
      sred[part * 64 + p] = sa;
      sred[256 + part * 64 + p] = sb;
      __syncthreads();
      if (tid < 128) {
        int odd = tid >> 6, pp = tid & 63;
        if (!(odd && ((pp & 3) == 3))) {
          float s = sred[odd * 256 + pp] + sred[odd * 256 + 64 + pp] +
                    sred[odd * 256 + 128 + pp] + sred[odd * 256 + 192 + pp];
          int n = (2 * pp + odd) & 7;  // 0..6
          atomicAdd(&simo[n], expf(-0.5f * s) * (1.0f / 16384.0f));
        }
      }
    }
  }
}

// One block per b: logits (dot of query with 8 masked keys), where(==0), softmax.
__global__ void attn_kernel(const float* __restrict__ query, const float* __restrict__ km,
                            float* __restrict__ logits, float* __restrict__ wts) {
  int b = blockIdx.x;
  int tid = threadIdx.x;
  int w = tid >> 6, lane = tid & 63;
  __shared__ float lg[8];
  __shared__ float post[8];
  __shared__ float ex[8];
  for (int n = w; n < 8; n += 4) {
    float p = 0.f;
    for (int k = lane; k < 384; k += 64)
      p += query[(size_t)b * 384 + k] * km[((size_t)b * 8 + n) * 384 + k];
    p = wave_sum(p);
    if (lane == 0) lg[n] = p * 0.08838834764831845f;  // 1/sqrt(128)
  }
  __syncthreads();
  if (tid < 8) {
    float l = lg[tid];
    l = (l == 0.0f) ? -1e9f : l;
    post[tid] = l;
    logits[(size_t)b * 8 + tid] = l;
  }
  __syncthreads();
  if (tid < 8) {
    float m = post[0];
#pragma unroll
    for (int i = 1; i < 8; ++i) m = fmaxf(m, post[i]);
    ex[tid] = expf(post[tid] - m);
  }
  __syncthreads();
  if (tid < 8) {
    float s = 0.f;
#pragma unroll
    for (int i = 0; i < 8; ++i) s += ex[i];
    wts[(size_t)b * 8 + tid] = ex[tid] / s;
  }
}

// Values GEMM + fused attend + q1. One block = one b (rows (b,n,a), all 8n x 16a).
__global__ __launch_bounds__(256) void v_gemm_attend(const float* __restrict__ sf,
                                                     const float* __restrict__ Wv,
                                                     const float* __restrict__ bv,
                                                     const float* __restrict__ wts,
                                                     const float* __restrict__ task,
                                                     float* __restrict__ vm,
                                                     float* __restrict__ att,
                                                     float* __restrict__ q1) {
  __shared__ unsigned short As[128 * 40];   // also reused as attL (f32 16x132) in epilogue
  __shared__ unsigned short Bs[128 * 136];
  float* attL = (float*)As;                 // 16*132*4 = 8448B <= 10240B
  int bid = blockIdx.x;
  int swz = (bid & 7) * 2048 + (bid >> 3);
  int b = swz;
  size_t m0 = (size_t)swz * 128;
  int tid = threadIdx.x;
  int wave = tid >> 6, lane = tid & 63;
  int wr = wave >> 1, wc = wave & 1;
  int r = tid >> 1, h = tid & 1;
  int la = lane & 15, lkq = lane >> 4;

  // stage B: Bs[n][k] = bf16(Wv[k][n]); coalesced f32 reads, scattered b16 LDS writes
#pragma unroll
  for (int q = 0; q < 16; ++q) {
    int flat = q * 256 + tid;         // 0..4095
    int k = flat >> 5;                // 0..127
    int n4 = (flat & 31) * 4;         // 0,4,..,124
    float4 v = *(const float4*)(Wv + (size_t)k * 128 + n4);
    Bs[(n4 + 0) * 136 + k] = f2bf(v.x);
    Bs[(n4 + 1) * 136 + k] = f2bf(v.y);
    Bs[(n4 + 2) * 136 + k] = f2bf(v.z);
    Bs[(n4 + 3) * 136 + k] = f2bf(v.w);
  }

  f32x4 acc[4][4];
#pragma unroll
  for (int i = 0; i < 4; ++i)
#pragma unroll
    for (int j = 0; j < 4; ++j) acc[i][j] = (f32x4)(0.f);

  for (int ks = 0; ks < 4; ++ks) {
    int k0 = ks * 32;
    const float* ap = sf + (m0 + r) * 128 + k0 + h * 16;
    float4 v0 = *(const float4*)(ap);
    float4 v1 = *(const float4*)(ap + 4);
    float4 v2 = *(const float4*)(ap + 8);
    float4 v3 = *(const float4*)(ap + 12);
    ushort4 p0 = make_ushort4(f2bf(v0.x), f2bf(v0.y), f2bf(v0.z), f2bf(v0.w));
    ushort4 p1 = make_ushort4(f2bf(v1.x), f2bf(v1.y), f2bf(v1.z), f2bf(v1.w));
    ushort4 p2 = make_ushort4(f2bf(v2.x), f2bf(v2.y), f2bf(v2.z), f2bf(v2.w));
    ushort4 p3 = make_ushort4(f2bf(v3.x), f2bf(v3.y), f2bf(v3.z), f2bf(v3.w));
    *(ushort4*)(As + r * 40 + h * 16)      = p0;
    *(ushort4*)(As + r * 40 + h * 16 + 4)  = p1;
    *(ushort4*)(As + r * 40 + h * 16 + 8)  = p2;
    *(ushort4*)(As + r * 40 + h * 16 + 12) = p3;
    __syncthreads();
    bf16x8 af[4], bfr[4];
#pragma unroll
    for (int mi = 0; mi < 4; ++mi)
      af[mi] = *(const bf16x8*)(As + (wr * 64 + mi * 16 + la) * 40 + lkq * 8);
#pragma unroll
    for (int ni = 0; ni < 4; ++ni)
      bfr[ni] = *(const bf16x8*)(Bs + (wc * 64 + ni * 16 + la) * 136 + k0 + lkq * 8);
#pragma unroll
    for (int mi = 0; mi < 4; ++mi)
#pragma unroll
      for (int ni = 0; ni < 4; ++ni)
        acc[mi][ni] = __builtin_amdgcn_mfma_f32_16x16x32_bf16(af[mi], bfr[ni], acc[mi][ni], 0, 0, 0);
    __syncthreads();
  }

  // epilogue: vm write + weighted partials over mi (n = wr*4+mi)
  float w4[4];
#pragma unroll
  for (int mi = 0; mi < 4; ++mi) w4[mi] = wts[(size_t)b * 8 + wr * 4 + mi];
  float pacc[4][4];  // [ni][j]
#pragma unroll
  for (int ni = 0; ni < 4; ++ni)
#pragma unroll
    for (int j = 0; j < 4; ++j) pacc[ni][j] = 0.f;
#pragma unroll
  for (int mi = 0; mi < 4; ++mi) {
#pragma unroll
    for (int ni = 0; ni < 4; ++ni) {
      int colg = wc * 64 + ni * 16 + la;
      float bb = bv[colg];
#pragma unroll
      for (int j = 0; j < 4; ++j) {
        size_t rowg = m0 + wr * 64 + mi * 16 + lkq * 4 + j;
        float v = acc[mi][ni][j] + bb;
        vm[rowg * 128 + colg] = v;
        pacc[ni][j] = fmaf(w4[mi], v, pacc[ni][j]);
      }
    }
  }
  // cross-wave (wr) reduce into attL[a][col], a = lkq*4+j
  if (wr == 0) {
#pragma unroll
    for (int ni = 0; ni < 4; ++ni)
#pragma unroll
      for (int j = 0; j < 4; ++j)
        attL[(lkq * 4 + j) * 132 + wc * 64 + ni * 16 + la] = pacc[ni][j];
  }
  __syncthreads();
  if (wr == 1) {
#pragma unroll
    for (int ni = 0; ni < 4; ++ni)
#pragma unroll
      for (int j = 0; j < 4; ++j)
        attL[(lkq * 4 + j) * 132 + wc * 64 + ni * 16 + la] += pacc[ni][j];
  }
  __syncthreads();
  // write attended (2048 f32) + q1 (16)
#pragma unroll
  for (int i = 0; i < 2; ++i) {
    int fidx = tid + i * 256;
    int a = fidx >> 5, c = (fidx & 31) * 4;
    f32x4 vv = *(const f32x4*)(attL + a * 132 + c);
    *(f32x4*)(att + (size_t)b * 2048 + a * 128 + c) = vv;
  }
  for (int j = wave; j < 16; j += 4) {
    float p = task[(size_t)b * 1024 + lane] * attL[j * 132 + lane]
            + task[(size_t)b * 1024 + 64 + lane] * attL[j * 132 + 64 + lane];
    p = wave_sum(p);
    if (lane == 0) q1[(size_t)b * 16 + j] = p;
  }
}

extern "C" void kernel_launch(void* const* d_in, const int* in_sizes, int n_in,
                              void* d_out, int out_size, void* d_ws, size_t ws_size,
                              hipStream_t stream) {
  const float* basis = (const float*)d_in[0];
  const float* sf    = (const float*)d_in[1];
  const float* task  = (const float*)d_in[2];
  const float* mask  = (const float*)d_in[3];
  const float* Wq    = (const float*)d_in[4];
  const float* Wk    = (const float*)d_in[5];
  const float* bk    = (const float*)d_in[6];
  const float* Wv    = (const float*)d_in[7];
  const float* bv    = (const float*)d_in[8];

  float* out  = (float*)d_out;
  float* q1   = out;
  float* att  = out + OFF_ATT;
  float* logi = out + OFF_LOG;
  float* wts  = out + OFF_W;
  float* km   = out + OFF_KM;
  float* vm   = out + OFF_VM;
  float* simo = out + OFF_SIM;

  // Stash plan: query/invn/WkT/WqT live in the att output region; all consumers
  // (qk_gemm_fused, attn_kernel) complete before v_gemm_attend — the only att
  // writer — launches. No stash in vm anymore (Abf eliminated this round).
  float* query = att;                                       // 6,291,456 f32
  float* invn  = att + 6291456;                             //   131,072 f32
  unsigned short* WkT = (unsigned short*)(att + 6422528);   //   884,736 bf16
  unsigned short* WqT = WkT + 884736;                       //   884,736 bf16

  norm_kernel<<<32768, 256, 0, stream>>>(task, invn, simo);
  wprep_t<<<216, 256, 0, stream>>>(Wk, WkT, 2304, 384);
  wprep_t<<<216, 256, 0, stream>>>(Wq, WqT, 2304, 384);
  // keys: M=131072, N=384 (3 n-tiles), K=2304; A built on-the-fly; fused sim
  qk_gemm_fused<0><<<3072, 256, 0, stream>>>(basis, sf, task, invn, WkT, bk, mask, km, simo);
  // query: M=16384 (underlying rows stride 8), N=384, K=2304
  qk_gemm_fused<1><<<384, 256, 0, stream>>>(basis, sf, task, invn, WqT, nullptr, nullptr, query, nullptr);
  attn_kernel<<<16384, 256, 0, stream>>>(query, km, logi, wts);
  // values GEMM + fused attend/q1: M=2,097,152, N=128, K=128
  v_gemm_attend<<<16384, 256, 0, stream>>>(sf, Wv, bv, wts, task, vm, att, q1);
}

// Round 7
// 1309.555 us; speedup vs baseline: 1.1745x; 1.1745x over previous
//
#include <hip/hip_runtime.h>
#include <hip/hip_bf16.h>
#include <math.h>

// B=16384, NB=8, NA=16, D=128, IN_DIM=2304, QK_DIM=384, V_DIM=128
static constexpr size_t OFF_ATT = 262144;      // attended_sf (33,554,432 f32)
static constexpr size_t OFF_LOG = 33816576;    // attn_logits
static constexpr size_t OFF_W   = 33947648;    // attention_weights
static constexpr size_t OFF_KM  = 34078720;    // keys_masked
static constexpr size_t OFF_VM  = 84410368;    // values_masked (268,435,456 f32)
static constexpr size_t OFF_SIM = 352845824;   // sim (7)

typedef short bf16x8 __attribute__((ext_vector_type(8)));
typedef float f32x4 __attribute__((ext_vector_type(4)));

__device__ inline unsigned short f2bf(float f) {
  union { float f; unsigned u; } x; x.f = f;
  unsigned r = x.u + 0x7FFFu + ((x.u >> 16) & 1u);  // RNE
  return (unsigned short)(r >> 16);
}

__device__ inline float wave_sum(float v) {
#pragma unroll
  for (int o = 32; o > 0; o >>= 1) v += __shfl_xor(v, o, 64);
  return v;
}

// One wave per (b,n) row: inverse L2 norm of task rows. Also zero sim slots.
__global__ void norm_kernel(const float* __restrict__ task, float* __restrict__ invn,
                            float* __restrict__ simo) {
  int idx = blockIdx.x * 4 + (threadIdx.x >> 6);
  int lane = threadIdx.x & 63;
  float t0 = task[(size_t)idx * 128 + lane];
  float t1 = task[(size_t)idx * 128 + 64 + lane];
  float s = wave_sum(t0 * t0 + t1 * t1);
  if (lane == 0) invn[idx] = rsqrtf(s);
  if (blockIdx.x == 0 && threadIdx.x < 7) simo[threadIdx.x] = 0.0f;
}

// Tiled transpose+cvt: WT[n][k] = bf16(W[k][n]). 64x64 tiles, coalesced both sides.
__global__ void wprep_t(const float* __restrict__ W, unsigned short* __restrict__ WT,
                        int K, int N) {
  int ntn = N >> 6;
  int kt = blockIdx.x / ntn, nt = blockIdx.x % ntn;
  int k0 = kt * 64, n0 = nt * 64;
  __shared__ float t[64][65];
  int tid = threadIdx.x;
  int r = tid >> 2, c0 = (tid & 3) * 16;
#pragma unroll
  for (int q = 0; q < 4; ++q) {
    float4 v = *(const float4*)(W + (size_t)(k0 + r) * N + n0 + c0 + q * 4);
    t[r][c0 + q * 4 + 0] = v.x; t[r][c0 + q * 4 + 1] = v.y;
    t[r][c0 + q * 4 + 2] = v.z; t[r][c0 + q * 4 + 3] = v.w;
  }
  __syncthreads();
  int n = tid >> 2, kc0 = (tid & 3) * 16;
#pragma unroll
  for (int q = 0; q < 4; ++q) {
    int kc = kc0 + q * 4;
    ushort4 o = make_ushort4(f2bf(t[kc + 0][n]), f2bf(t[kc + 1][n]),
                             f2bf(t[kc + 2][n]), f2bf(t[kc + 3][n]));
    *(ushort4*)(WT + (size_t)(n0 + n) * K + k0 + kc) = o;
  }
}

// One block (576 thr) per b: thread owns one float4-chunk f of the 2304-row.
// Loads all 8 rows' chunks (independent), writes bf16 Abf, and accumulates the
// 7 consecutive-row squared-diff partials in registers.
__global__ __launch_bounds__(576) void abuild_sim(const float* __restrict__ basis,
                                                  const float* __restrict__ sf,
                                                  const float* __restrict__ task,
                                                  const float* __restrict__ invn,
                                                  unsigned short* __restrict__ Abf,
                                                  float* __restrict__ simo) {
  int b = blockIdx.x;
  int f = threadIdx.x;  // 0..575
  size_t row0 = (size_t)b * 8;
  float4 v[8];
#pragma unroll
  for (int n = 0; n < 8; ++n) {
    size_t row = row0 + n;
    float4 x;
    if (f < 32)       x = *(const float4*)(basis + row * 128 + f * 4);
    else if (f < 544) x = *(const float4*)(sf + row * 2048 + (f - 32) * 4);
    else {
      x = *(const float4*)(task + row * 128 + (f - 544) * 4);
      float s = invn[row];
      x.x *= s; x.y *= s; x.z *= s; x.w *= s;
    }
    v[n] = x;
    ushort4 o = make_ushort4(f2bf(x.x), f2bf(x.y), f2bf(x.z), f2bf(x.w));
    *(ushort4*)(Abf + row * 2304 + f * 4) = o;
  }
  float s7[7];
#pragma unroll
  for (int n = 1; n < 8; ++n) {
    float dx = v[n].x - v[n - 1].x, dy = v[n].y - v[n - 1].y;
    float dz = v[n].z - v[n - 1].z, dw = v[n].w - v[n - 1].w;
    s7[n - 1] = dx * dx + dy * dy + dz * dz + dw * dw;
  }
  __shared__ float red[9][7];
  int wid = threadIdx.x >> 6, lane = threadIdx.x & 63;
#pragma unroll
  for (int i = 0; i < 7; ++i) {
    float p = wave_sum(s7[i]);
    if (lane == 0) red[wid][i] = p;
  }
  __syncthreads();
  if (threadIdx.x < 7) {
    float s = 0.f;
#pragma unroll
    for (int w = 0; w < 9; ++w) s += red[w][threadIdx.x];
    atomicAdd(&simo[threadIdx.x], expf(-0.5f * s) * (1.0f / 16384.0f));
  }
}

// MFMA GEMM for keys (MODE 0) / query (MODE 1): out[M x 384] = Abf rows @ WT^T.
// 128x128 tile, BK=32, 4 waves (2x2 of 64x64). global_load_lds (16B) staging into
// double-buffered linear LDS [128][32] bf16 (m97 structure).
template <int MODE>
__global__ __launch_bounds__(256) void qk_gemm(const unsigned short* __restrict__ Abf,
                                               const unsigned short* __restrict__ WT,
                                               const float* __restrict__ bias,
                                               const float* __restrict__ mask,
                                               float* __restrict__ outp) {
  __shared__ unsigned short As[2 * 4096];
  __shared__ unsigned short Bs[2 * 4096];
  int nwg = gridDim.x, per = nwg >> 3;
  int bid = blockIdx.x;
  int swz = (bid & 7) * per + (bid >> 3);
  int mt = swz / 3, nt = swz - mt * 3;
  int tid = threadIdx.x;
  int wave = tid >> 6, lane = tid & 63;
  int wr = wave >> 1, wc = wave & 1;
  int m0g = mt * 128, n0g = nt * 128;

  // staging geometry: chunk c = (wave*2+q)*64 + lane; row = c>>2, kc = (c&3)*8
  int c_lo = wave * 2 * 64 + lane;          // q=0 chunk index
  int row_q0 = c_lo >> 2, kc_q0 = (c_lo & 3) * 8;
  int c_hi = c_lo + 64;                     // q=1
  int row_q1 = c_hi >> 2, kc_q1 = (c_hi & 3) * 8;
  size_t ga_q0 = (MODE == 1) ? (size_t)(m0g + row_q0) * 8 : (size_t)(m0g + row_q0);
  size_t ga_q1 = (MODE == 1) ? (size_t)(m0g + row_q1) * 8 : (size_t)(m0g + row_q1);
  const unsigned short* ag0 = Abf + ga_q0 * 2304 + kc_q0;
  const unsigned short* ag1 = Abf + ga_q1 * 2304 + kc_q1;
  const unsigned short* bg0 = WT + (size_t)(n0g + row_q0) * 2304 + kc_q0;
  const unsigned short* bg1 = WT + (size_t)(n0g + row_q1) * 2304 + kc_q1;
  int ldsoff0 = wave * 2 * 512;             // elements; uniform per wave
  int ldsoff1 = ldsoff0 + 512;

#define STAGE(ks, cur)                                                                   \
  do {                                                                                   \
    int _k0 = (ks) * 32;                                                                 \
    unsigned short* _a = As + (cur) * 4096;                                              \
    unsigned short* _b = Bs + (cur) * 4096;                                              \
    __builtin_amdgcn_global_load_lds(                                                    \
        (const __attribute__((address_space(1))) void*)(ag0 + _k0),                      \
        (__attribute__((address_space(3))) void*)(_a + ldsoff0), 16, 0, 0);              \
    __builtin_amdgcn_global_load_lds(                                                    \
        (const __attribute__((address_space(1))) void*)(ag1 + _k0),                      \
        (__attribute__((address_space(3))) void*)(_a + ldsoff1), 16, 0, 0);              \
    __builtin_amdgcn_global_load_lds(                                                    \
        (const __attribute__((address_space(1))) void*)(bg0 + _k0),                      \
        (__attribute__((address_space(3))) void*)(_b + ldsoff0), 16, 0, 0);              \
    __builtin_amdgcn_global_load_lds(                                                    \
        (const __attribute__((address_space(1))) void*)(bg1 + _k0),                      \
        (__attribute__((address_space(3))) void*)(_b + ldsoff1), 16, 0, 0);              \
  } while (0)

  f32x4 acc[4][4];
#pragma unroll
  for (int i = 0; i < 4; ++i)
#pragma unroll
    for (int j = 0; j < 4; ++j) acc[i][j] = (f32x4)(0.f);

  int la = lane & 15, lk = (lane >> 4) * 8;

  STAGE(0, 0);
  __syncthreads();
  int cur = 0;
  for (int ks = 0; ks < 72; ++ks) {
    if (ks < 71) STAGE(ks + 1, cur ^ 1);   // prefetch overlaps ds_read+MFMA below
    const unsigned short* aL = As + cur * 4096;
    const unsigned short* bL = Bs + cur * 4096;
    bf16x8 af[4], bf[4];
#pragma unroll
    for (int mi = 0; mi < 4; ++mi)
      af[mi] = *(const bf16x8*)(aL + (wr * 64 + mi * 16 + la) * 32 + lk);
#pragma unroll
    for (int ni = 0; ni < 4; ++ni)
      bf[ni] = *(const bf16x8*)(bL + (wc * 64 + ni * 16 + la) * 32 + lk);
#pragma unroll
    for (int mi = 0; mi < 4; ++mi)
#pragma unroll
      for (int ni = 0; ni < 4; ++ni)
        acc[mi][ni] = __builtin_amdgcn_mfma_f32_16x16x32_bf16(af[mi], bf[ni], acc[mi][ni], 0, 0, 0);
    __syncthreads();
    cur ^= 1;
  }
#undef STAGE

  int rq = lane >> 4;
#pragma unroll
  for (int mi = 0; mi < 4; ++mi) {
#pragma unroll
    for (int ni = 0; ni < 4; ++ni) {
      int colg = nt * 128 + wc * 64 + ni * 16 + la;
#pragma unroll
      for (int j = 0; j < 4; ++j) {
        int rowg = mt * 128 + wr * 64 + mi * 16 + rq * 4 + j;
        float v = acc[mi][ni][j];
        if (MODE == 0)
          v = (v + bias[colg]) * mask[(size_t)rowg * 128 + (unsigned)colg / 3u];
        outp[(size_t)rowg * 384 + colg] = v;
      }
    }
  }
}

// 4 b per block, one wave per b: logits + where(==0) + softmax. Zero LDS/barriers.
__global__ __launch_bounds__(256) void attn_kernel4(const float* __restrict__ query,
                                                    const float* __restrict__ km,
                                                    float* __restrict__ logits,
                                                    float* __restrict__ wts) {
  int w = threadIdx.x >> 6, lane = threadIdx.x & 63;
  int b = blockIdx.x * 4 + w;
  float q[6];
#pragma unroll
  for (int j = 0; j < 6; ++j) q[j] = query[(size_t)b * 384 + lane + 64 * j];
  float lg[8];
#pragma unroll
  for (int n = 0; n < 8; ++n) {
    const float* kr = km + ((size_t)b * 8 + n) * 384;
    float p = 0.f;
#pragma unroll
    for (int j = 0; j < 6; ++j) p = fmaf(q[j], kr[lane + 64 * j], p);
    p = wave_sum(p);
    float l = p * 0.08838834764831845f;  // 1/sqrt(128)
    lg[n] = (l == 0.0f) ? -1e9f : l;
  }
  float m = lg[0];
#pragma unroll
  for (int i = 1; i < 8; ++i) m = fmaxf(m, lg[i]);
  float ex[8], s = 0.f;
#pragma unroll
  for (int i = 0; i < 8; ++i) { ex[i] = expf(lg[i] - m); s += ex[i]; }
  float inv = 1.0f / s;
  if (lane < 8) {
    float lv = lg[0], ev = ex[0];
#pragma unroll
    for (int i = 1; i < 8; ++i)
      if (lane == i) { lv = lg[i]; ev = ex[i]; }
    logits[(size_t)b * 8 + lane] = lv;
    wts[(size_t)b * 8 + lane] = ev * inv;
  }
}

// Values GEMM + fused attend + q1. One block = one b (rows (b,n,a), all 8n x 16a).
// ABF=1: A from Abf's sf-section (bf16, d_ws), B from WvT (bf16, d_ws).
// ABF=0: A from sf f32 (inline cvt), B transposed in-block from Wv f32 (round-5 path).
template <int ABF>
__global__ __launch_bounds__(256) void v_gemm_attend(const float* __restrict__ sf,
                                                     const unsigned short* __restrict__ Abf,
                                                     const float* __restrict__ Wv,
                                                     const unsigned short* __restrict__ WvT,
                                                     const float* __restrict__ bv,
                                                     const float* __restrict__ wts,
                                                     const float* __restrict__ task,
                                                     float* __restrict__ vm,
                                                     float* __restrict__ att,
                                                     float* __restrict__ q1) {
  __shared__ unsigned short As[128 * 40];   // also reused as attL (f32 16x132) in epilogue
  __shared__ unsigned short Bs[128 * 136];
  float* attL = (float*)As;                 // 16*132*4 = 8448B <= 10240B
  int bid = blockIdx.x;
  int swz = (bid & 7) * 2048 + (bid >> 3);
  int b = swz;
  size_t m0 = (size_t)swz * 128;
  int tid = threadIdx.x;
  int wave = tid >> 6, lane = tid & 63;
  int wr = wave >> 1, wc = wave & 1;
  int r = tid >> 1, h = tid & 1;
  int la = lane & 15, lkq = lane >> 4;

  if (ABF) {
    // stage B from prebuilt WvT bf16 [128][128] (L2-resident): 8x b128 per thread
#pragma unroll
    for (int q = 0; q < 8; ++q) {
      bf16x8 v = *(const bf16x8*)(WvT + (size_t)r * 128 + h * 64 + q * 8);
      *(bf16x8*)(Bs + r * 136 + h * 64 + q * 8) = v;
    }
  } else {
    // stage B: Bs[n][k] = bf16(Wv[k][n]); coalesced f32 reads, scattered b16 writes
#pragma unroll
    for (int q = 0; q < 16; ++q) {
      int flat = q * 256 + tid;
      int k = flat >> 5;
      int n4 = (flat & 31) * 4;
      float4 v = *(const float4*)(Wv + (size_t)k * 128 + n4);
      Bs[(n4 + 0) * 136 + k] = f2bf(v.x);
      Bs[(n4 + 1) * 136 + k] = f2bf(v.y);
      Bs[(n4 + 2) * 136 + k] = f2bf(v.z);
      Bs[(n4 + 3) * 136 + k] = f2bf(v.w);
    }
  }

  // A source for ABF=1: tile row tr=(n,a) -> Abf[(b*8+n)*2304 + 128 + a*128 + k]
  const unsigned short* abase = nullptr;
  if (ABF) {
    int n = r >> 4, a = r & 15;
    abase = Abf + ((size_t)b * 8 + n) * 2304 + 128 + (size_t)a * 128 + h * 16;
  }

  f32x4 acc[4][4];
#pragma unroll
  for (int i = 0; i < 4; ++i)
#pragma unroll
    for (int j = 0; j < 4; ++j) acc[i][j] = (f32x4)(0.f);

  for (int ks = 0; ks < 4; ++ks) {
    int k0 = ks * 32;
    if (ABF) {
      bf16x8 u0 = *(const bf16x8*)(abase + k0);
      bf16x8 u1 = *(const bf16x8*)(abase + k0 + 8);
      *(bf16x8*)(As + r * 40 + h * 16)     = u0;
      *(bf16x8*)(As + r * 40 + h * 16 + 8) = u1;
    } else {
      const float* ap = sf + (m0 + r) * 128 + k0 + h * 16;
      float4 v0 = *(const float4*)(ap);
      float4 v1 = *(const float4*)(ap + 4);
      float4 v2 = *(const float4*)(ap + 8);
      float4 v3 = *(const float4*)(ap + 12);
      ushort4 p0 = make_ushort4(f2bf(v0.x), f2bf(v0.y), f2bf(v0.z), f2bf(v0.w));
      ushort4 p1 = make_ushort4(f2bf(v1.x), f2bf(v1.y), f2bf(v1.z), f2bf(v1.w));
      ushort4 p2 = make_ushort4(f2bf(v2.x), f2bf(v2.y), f2bf(v2.z), f2bf(v2.w));
      ushort4 p3 = make_ushort4(f2bf(v3.x), f2bf(v3.y), f2bf(v3.z), f2bf(v3.w));
      *(ushort4*)(As + r * 40 + h * 16)      = p0;
      *(ushort4*)(As + r * 40 + h * 16 + 4)  = p1;
      *(ushort4*)(As + r * 40 + h * 16 + 8)  = p2;
      *(ushort4*)(As + r * 40 + h * 16 + 12) = p3;
    }
    __syncthreads();
    bf16x8 af[4], bfr[4];
#pragma unroll
    for (int mi = 0; mi < 4; ++mi)
      af[mi] = *(const bf16x8*)(As + (wr * 64 + mi * 16 + la) * 40 + lkq * 8);
#pragma unroll
    for (int ni = 0; ni < 4; ++ni)
      bfr[ni] = *(const bf16x8*)(Bs + (wc * 64 + ni * 16 + la) * 136 + k0 + lkq * 8);
#pragma unroll
    for (int mi = 0; mi < 4; ++mi)
#pragma unroll
      for (int ni = 0; ni < 4; ++ni)
        acc[mi][ni] = __builtin_amdgcn_mfma_f32_16x16x32_bf16(af[mi], bfr[ni], acc[mi][ni], 0, 0, 0);
    __syncthreads();
  }

  // epilogue: vm write + weighted partials over mi (n = wr*4+mi)
  float w4[4];
#pragma unroll
  for (int mi = 0; mi < 4; ++mi) w4[mi] = wts[(size_t)b * 8 + wr * 4 + mi];
  float pacc[4][4];  // [ni][j]
#pragma unroll
  for (int ni = 0; ni < 4; ++ni)
#pragma unroll
    for (int j = 0; j < 4; ++j) pacc[ni][j] = 0.f;
#pragma unroll
  for (int mi = 0; mi < 4; ++mi) {
#pragma unroll
    for (int ni = 0; ni < 4; ++ni) {
      int colg = wc * 64 + ni * 16 + la;
      float bb = bv[colg];
#pragma unroll
      for (int j = 0; j < 4; ++j) {
        size_t rowg = m0 + wr * 64 + mi * 16 + lkq * 4 + j;
        float v = acc[mi][ni][j] + bb;
        vm[rowg * 128 + colg] = v;
        pacc[ni][j] = fmaf(w4[mi], v, pacc[ni][j]);
      }
    }
  }
  // cross-wave (wr) reduce into attL[a][col], a = lkq*4+j
  if (wr == 0) {
#pragma unroll
    for (int ni = 0; ni < 4; ++ni)
#pragma unroll
      for (int j = 0; j < 4; ++j)
        attL[(lkq * 4 + j) * 132 + wc * 64 + ni * 16 + la] = pacc[ni][j];
  }
  __syncthreads();
  if (wr == 1) {
#pragma unroll
    for (int ni = 0; ni < 4; ++ni)
#pragma unroll
      for (int j = 0; j < 4; ++j)
        attL[(lkq * 4 + j) * 132 + wc * 64 + ni * 16 + la] += pacc[ni][j];
  }
  __syncthreads();
  // write attended (2048 f32) + q1 (16)
#pragma unroll
  for (int i = 0; i < 2; ++i) {
    int fidx = tid + i * 256;
    int a = fidx >> 5, c = (fidx & 31) * 4;
    f32x4 vv = *(const f32x4*)(attL + a * 132 + c);
    *(f32x4*)(att + (size_t)b * 2048 + a * 128 + c) = vv;
  }
  for (int j = wave; j < 16; j += 4) {
    float p = task[(size_t)b * 1024 + lane] * attL[j * 132 + lane]
            + task[(size_t)b * 1024 + 64 + lane] * attL[j * 132 + 64 + lane];
    p = wave_sum(p);
    if (lane == 0) q1[(size_t)b * 16 + j] = p;
  }
}

extern "C" void kernel_launch(void* const* d_in, const int* in_sizes, int n_in,
                              void* d_out, int out_size, void* d_ws, size_t ws_size,
                              hipStream_t stream) {
  const float* basis = (const float*)d_in[0];
  const float* sf    = (const float*)d_in[1];
  const float* task  = (const float*)d_in[2];
  const float* mask  = (const float*)d_in[3];
  const float* Wq    = (const float*)d_in[4];
  const float* Wk    = (const float*)d_in[5];
  const float* bk    = (const float*)d_in[6];
  const float* Wv    = (const float*)d_in[7];
  const float* bv    = (const float*)d_in[8];

  float* out  = (float*)d_out;
  float* q1   = out;
  float* att  = out + OFF_ATT;
  float* logi = out + OFF_LOG;
  float* wts  = out + OFF_W;
  float* km   = out + OFF_KM;
  float* vm   = out + OFF_VM;
  float* simo = out + OFF_SIM;

  // d_ws layout (preferred path): Abf | WkT | WqT | WvT | query | invn = ~634MB.
  // Disjoint from all outputs -> no stash-lifetime hazards at all.
  constexpr size_t WS_NEED = 603979776ull + 1769472ull + 1769472ull + 32768ull +
                             25165824ull + 524288ull;
  bool usews = ws_size >= WS_NEED;

  unsigned short *Abf, *WkT, *WqT, *WvT = nullptr;
  float *query, *invn;
  if (usews) {
    unsigned char* ws = (unsigned char*)d_ws;
    Abf   = (unsigned short*)ws;
    WkT   = (unsigned short*)(ws + 603979776ull);
    WqT   = (unsigned short*)(ws + 605749248ull);
    WvT   = (unsigned short*)(ws + 607518720ull);
    query = (float*)(ws + 607551488ull);
    invn  = (float*)(ws + 632717312ull);
  } else {
    // round-5 fallback stashes: Abf in vm region (consumed by qk_gemms before
    // v_gemm_attend overwrites vm); query/invn/WkT/WqT in att region (all
    // consumed before v_gemm_attend, the only att writer, launches).
    query = att;                                     // 6,291,456 f32
    invn  = att + 6291456;                           //   131,072 f32
    WkT   = (unsigned short*)(att + 6422528);        //   884,736 bf16
    WqT   = WkT + 884736;                            //   884,736 bf16
    Abf   = (unsigned short*)vm;                     // 301,989,888 bf16
  }

  norm_kernel<<<32768, 256, 0, stream>>>(task, invn, simo);
  wprep_t<<<216, 256, 0, stream>>>(Wk, WkT, 2304, 384);
  wprep_t<<<216, 256, 0, stream>>>(Wq, WqT, 2304, 384);
  if (usews) wprep_t<<<4, 256, 0, stream>>>(Wv, WvT, 128, 128);
  abuild_sim<<<16384, 576, 0, stream>>>(basis, sf, task, invn, Abf, simo);
  // keys: M=131072, N=384 (3 n-tiles), K=2304; bias + mask
  qk_gemm<0><<<3072, 256, 0, stream>>>(Abf, WkT, bk, mask, km);
  // query: M=16384 (Abf rows stride 8), N=384, K=2304
  qk_gemm<1><<<384, 256, 0, stream>>>(Abf, WqT, nullptr, nullptr, query);
  attn_kernel4<<<4096, 256, 0, stream>>>(query, km, logi, wts);
  // values GEMM + fused attend/q1: M=2,097,152, N=128, K=128
  if (usews)
    v_gemm_attend<1><<<16384, 256, 0, stream>>>(sf, Abf, Wv, WvT, bv, wts, task, vm, att, q1);
  else
    v_gemm_attend<0><<<16384, 256, 0, stream>>>(sf, Abf, Wv, WvT, bv, wts, task, vm, att, q1);
}

// Round 8
// 1282.686 us; speedup vs baseline: 1.1991x; 1.0209x over previous
//
#include <hip/hip_runtime.h>
#include <hip/hip_bf16.h>
#include <math.h>

// B=16384, NB=8, NA=16, D=128, IN_DIM=2304, QK_DIM=384, V_DIM=128
static constexpr size_t OFF_ATT = 262144;      // attended_sf (33,554,432 f32)
static constexpr size_t OFF_LOG = 33816576;    // attn_logits
static constexpr size_t OFF_W   = 33947648;    // attention_weights
static constexpr size_t OFF_KM  = 34078720;    // keys_masked
static constexpr size_t OFF_VM  = 84410368;    // values_masked (268,435,456 f32)
static constexpr size_t OFF_SIM = 352845824;   // sim (7)

typedef short bf16x8 __attribute__((ext_vector_type(8)));
typedef float f32x4 __attribute__((ext_vector_type(4)));

__device__ inline unsigned short f2bf(float f) {
  union { float f; unsigned u; } x; x.f = f;
  unsigned r = x.u + 0x7FFFu + ((x.u >> 16) & 1u);  // RNE
  return (unsigned short)(r >> 16);
}

__device__ inline float wave_sum(float v) {
#pragma unroll
  for (int o = 32; o > 0; o >>= 1) v += __shfl_xor(v, o, 64);
  return v;
}

// One wave per (b,n) row: inverse L2 norm of task rows. Also zero sim slots.
__global__ void norm_kernel(const float* __restrict__ task, float* __restrict__ invn,
                            float* __restrict__ simo) {
  int idx = blockIdx.x * 4 + (threadIdx.x >> 6);
  int lane = threadIdx.x & 63;
  float t0 = task[(size_t)idx * 128 + lane];
  float t1 = task[(size_t)idx * 128 + 64 + lane];
  float s = wave_sum(t0 * t0 + t1 * t1);
  if (lane == 0) invn[idx] = rsqrtf(s);
  if (blockIdx.x == 0 && threadIdx.x < 7) simo[threadIdx.x] = 0.0f;
}

// Tiled transpose+cvt: WT[n][k] = bf16(W[k][n]). 64x64 tiles, coalesced both sides.
__global__ void wprep_t(const float* __restrict__ W, unsigned short* __restrict__ WT,
                        int K, int N) {
  int ntn = N >> 6;
  int kt = blockIdx.x / ntn, nt = blockIdx.x % ntn;
  int k0 = kt * 64, n0 = nt * 64;
  __shared__ float t[64][65];
  int tid = threadIdx.x;
  int r = tid >> 2, c0 = (tid & 3) * 16;
#pragma unroll
  for (int q = 0; q < 4; ++q) {
    float4 v = *(const float4*)(W + (size_t)(k0 + r) * N + n0 + c0 + q * 4);
    t[r][c0 + q * 4 + 0] = v.x; t[r][c0 + q * 4 + 1] = v.y;
    t[r][c0 + q * 4 + 2] = v.z; t[r][c0 + q * 4 + 3] = v.w;
  }
  __syncthreads();
  int n = tid >> 2, kc0 = (tid & 3) * 16;
#pragma unroll
  for (int q = 0; q < 4; ++q) {
    int kc = kc0 + q * 4;
    ushort4 o = make_ushort4(f2bf(t[kc + 0][n]), f2bf(t[kc + 1][n]),
                             f2bf(t[kc + 2][n]), f2bf(t[kc + 3][n]));
    *(ushort4*)(WT + (size_t)(n0 + n) * K + k0 + kc) = o;
  }
}

// One block (576 thr) per b: thread owns one float4-chunk f of the 2304-row.
__global__ __launch_bounds__(576) void abuild_sim(const float* __restrict__ basis,
                                                  const float* __restrict__ sf,
                                                  const float* __restrict__ task,
                                                  const float* __restrict__ invn,
                                                  unsigned short* __restrict__ Abf,
                                                  float* __restrict__ simo) {
  int b = blockIdx.x;
  int f = threadIdx.x;  // 0..575
  size_t row0 = (size_t)b * 8;
  float4 v[8];
#pragma unroll
  for (int n = 0; n < 8; ++n) {
    size_t row = row0 + n;
    float4 x;
    if (f < 32)       x = *(const float4*)(basis + row * 128 + f * 4);
    else if (f < 544) x = *(const float4*)(sf + row * 2048 + (f - 32) * 4);
    else {
      x = *(const float4*)(task + row * 128 + (f - 544) * 4);
      float s = invn[row];
      x.x *= s; x.y *= s; x.z *= s; x.w *= s;
    }
    v[n] = x;
    ushort4 o = make_ushort4(f2bf(x.x), f2bf(x.y), f2bf(x.z), f2bf(x.w));
    *(ushort4*)(Abf + row * 2304 + f * 4) = o;
  }
  float s7[7];
#pragma unroll
  for (int n = 1; n < 8; ++n) {
    float dx = v[n].x - v[n - 1].x, dy = v[n].y - v[n - 1].y;
    float dz = v[n].z - v[n - 1].z, dw = v[n].w - v[n - 1].w;
    s7[n - 1] = dx * dx + dy * dy + dz * dz + dw * dw;
  }
  __shared__ float red[9][7];
  int wid = threadIdx.x >> 6, lane = threadIdx.x & 63;
#pragma unroll
  for (int i = 0; i < 7; ++i) {
    float p = wave_sum(s7[i]);
    if (lane == 0) red[wid][i] = p;
  }
  __syncthreads();
  if (threadIdx.x < 7) {
    float s = 0.f;
#pragma unroll
    for (int w = 0; w < 9; ++w) s += red[w][threadIdx.x];
    atomicAdd(&simo[threadIdx.x], expf(-0.5f * s) * (1.0f / 16384.0f));
  }
}

// MFMA GEMM for keys (MODE 0) / query (MODE 1): out[M x 384] = Abf rows @ WT^T.
// 128x128 tile, BK=32, 4 waves. global_load_lds into linear double-buffered LDS
// with XOR-swizzle applied via pre-swizzled GLOBAL source + swizzled ds_read
// (rule #21: involution data_slot = phys_slot ^ ((row>>1)&3)). Breaks the 8-way
// bank conflict of the linear layout down to 2-way-optimal.
template <int MODE>
__global__ __launch_bounds__(256) void qk_gemm(const unsigned short* __restrict__ Abf,
                                               const unsigned short* __restrict__ WT,
                                               const float* __restrict__ bias,
                                               const float* __restrict__ mask,
                                               float* __restrict__ outp) {
  __shared__ unsigned short As[2 * 4096];
  __shared__ unsigned short Bs[2 * 4096];
  int nwg = gridDim.x, per = nwg >> 3;
  int bid = blockIdx.x;
  int swz = (bid & 7) * per + (bid >> 3);
  int mt = swz / 3, nt = swz - mt * 3;
  int tid = threadIdx.x;
  int wave = tid >> 6, lane = tid & 63;
  int wr = wave >> 1, wc = wave & 1;
  int m0g = mt * 128, n0g = nt * 128;

  // staging: physical chunk p = wave*128 + lane (+64); row = p>>2;
  // source slot = (p&3) ^ ((row>>1)&3)  [inverse of the read swizzle]
  int c_lo = wave * 128 + lane;
  int row_q0 = c_lo >> 2, kc_q0 = ((c_lo & 3) ^ ((row_q0 >> 1) & 3)) * 8;
  int c_hi = c_lo + 64;
  int row_q1 = c_hi >> 2, kc_q1 = ((c_hi & 3) ^ ((row_q1 >> 1) & 3)) * 8;
  size_t ga_q0 = (MODE == 1) ? (size_t)(m0g + row_q0) * 8 : (size_t)(m0g + row_q0);
  size_t ga_q1 = (MODE == 1) ? (size_t)(m0g + row_q1) * 8 : (size_t)(m0g + row_q1);
  const unsigned short* ag0 = Abf + ga_q0 * 2304 + kc_q0;
  const unsigned short* ag1 = Abf + ga_q1 * 2304 + kc_q1;
  const unsigned short* bg0 = WT + (size_t)(n0g + row_q0) * 2304 + kc_q0;
  const unsigned short* bg1 = WT + (size_t)(n0g + row_q1) * 2304 + kc_q1;
  int ldsoff0 = wave * 1024;  // elements; wave-uniform (HW adds lane*16B)
  int ldsoff1 = ldsoff0 + 512;

#define STAGE(ks, cur)                                                                   \
  do {                                                                                   \
    int _k0 = (ks) * 32;                                                                 \
    unsigned short* _a = As + (cur) * 4096;                                              \
    unsigned short* _b = Bs + (cur) * 4096;                                              \
    __builtin_amdgcn_global_load_lds(                                                    \
        (const __attribute__((address_space(1))) void*)(ag0 + _k0),                      \
        (__attribute__((address_space(3))) void*)(_a + ldsoff0), 16, 0, 0);              \
    __builtin_amdgcn_global_load_lds(                                                    \
        (const __attribute__((address_space(1))) void*)(ag1 + _k0),                      \
        (__attribute__((address_space(3))) void*)(_a + ldsoff1), 16, 0, 0);              \
    __builtin_amdgcn_global_load_lds(                                                    \
        (const __attribute__((address_space(1))) void*)(bg0 + _k0),                      \
        (__attribute__((address_space(3))) void*)(_b + ldsoff0), 16, 0, 0);              \
    __builtin_amdgcn_global_load_lds(                                                    \
        (const __attribute__((address_space(1))) void*)(bg1 + _k0),                      \
        (__attribute__((address_space(3))) void*)(_b + ldsoff1), 16, 0, 0);              \
  } while (0)

  f32x4 acc[4][4];
#pragma unroll
  for (int i = 0; i < 4; ++i)
#pragma unroll
    for (int j = 0; j < 4; ++j) acc[i][j] = (f32x4)(0.f);

  int la = lane & 15;
  int sl = (((lane >> 4) ^ ((la >> 1) & 3))) * 8;  // swizzled k-slot for reads

  STAGE(0, 0);
  __syncthreads();
  int cur = 0;
  for (int ks = 0; ks < 72; ++ks) {
    if (ks < 71) STAGE(ks + 1, cur ^ 1);   // prefetch overlaps ds_read+MFMA below
    const unsigned short* aL = As + cur * 4096;
    const unsigned short* bL = Bs + cur * 4096;
    bf16x8 af[4], bf[4];
#pragma unroll
    for (int mi = 0; mi < 4; ++mi)
      af[mi] = *(const bf16x8*)(aL + (wr * 64 + mi * 16 + la) * 32 + sl);
#pragma unroll
    for (int ni = 0; ni < 4; ++ni)
      bf[ni] = *(const bf16x8*)(bL + (wc * 64 + ni * 16 + la) * 32 + sl);
#pragma unroll
    for (int mi = 0; mi < 4; ++mi)
#pragma unroll
      for (int ni = 0; ni < 4; ++ni)
        acc[mi][ni] = __builtin_amdgcn_mfma_f32_16x16x32_bf16(af[mi], bf[ni], acc[mi][ni], 0, 0, 0);
    __syncthreads();
    cur ^= 1;
  }
#undef STAGE

  int rq = lane >> 4;
#pragma unroll
  for (int mi = 0; mi < 4; ++mi) {
#pragma unroll
    for (int ni = 0; ni < 4; ++ni) {
      int colg = nt * 128 + wc * 64 + ni * 16 + la;
#pragma unroll
      for (int j = 0; j < 4; ++j) {
        int rowg = mt * 128 + wr * 64 + mi * 16 + rq * 4 + j;
        float v = acc[mi][ni][j];
        if (MODE == 0)
          v = (v + bias[colg]) * mask[(size_t)rowg * 128 + (unsigned)colg / 3u];
        outp[(size_t)rowg * 384 + colg] = v;
      }
    }
  }
}

// 4 b per block, one wave per b: logits + where(==0) + softmax. Zero LDS/barriers.
__global__ __launch_bounds__(256) void attn_kernel4(const float* __restrict__ query,
                                                    const float* __restrict__ km,
                                                    float* __restrict__ logits,
                                                    float* __restrict__ wts) {
  int w = threadIdx.x >> 6, lane = threadIdx.x & 63;
  int b = blockIdx.x * 4 + w;
  float q[6];
#pragma unroll
  for (int j = 0; j < 6; ++j) q[j] = query[(size_t)b * 384 + lane + 64 * j];
  float lg[8];
#pragma unroll
  for (int n = 0; n < 8; ++n) {
    const float* kr = km + ((size_t)b * 8 + n) * 384;
    float p = 0.f;
#pragma unroll
    for (int j = 0; j < 6; ++j) p = fmaf(q[j], kr[lane + 64 * j], p);
    p = wave_sum(p);
    float l = p * 0.08838834764831845f;  // 1/sqrt(128)
    lg[n] = (l == 0.0f) ? -1e9f : l;
  }
  float m = lg[0];
#pragma unroll
  for (int i = 1; i < 8; ++i) m = fmaxf(m, lg[i]);
  float ex[8], s = 0.f;
#pragma unroll
  for (int i = 0; i < 8; ++i) { ex[i] = expf(lg[i] - m); s += ex[i]; }
  float inv = 1.0f / s;
  if (lane < 8) {
    float lv = lg[0], ev = ex[0];
#pragma unroll
    for (int i = 1; i < 8; ++i)
      if (lane == i) { lv = lg[i]; ev = ex[i]; }
    logits[(size_t)b * 8 + lane] = lv;
    wts[(size_t)b * 8 + lane] = ev * inv;
  }
}

// Values GEMM + fused attend + q1. One block = one b (rows (b,n,a), all 8n x 16a).
// ABF=1: A from Abf's sf-section via global_load_lds + XOR swizzle (same scheme
// as qk_gemm), B from WvT bf16. ABF=0: round-5 reg-staged fallback.
template <int ABF>
__global__ __launch_bounds__(256) void v_gemm_attend(const float* __restrict__ sf,
                                                     const unsigned short* __restrict__ Abf,
                                                     const float* __restrict__ Wv,
                                                     const unsigned short* __restrict__ WvT,
                                                     const float* __restrict__ bv,
                                                     const float* __restrict__ wts,
                                                     const float* __restrict__ task,
                                                     float* __restrict__ vm,
                                                     float* __restrict__ att,
                                                     float* __restrict__ q1) {
  __shared__ unsigned short As[2 * 4096];   // ABF=1: [2][128][32]; ABF=0: [128][40] in low part
  __shared__ unsigned short Bs[128 * 136];
  float* attL = (float*)As;                 // 16*132*4 = 8448B <= 16KB, used after last barrier
  int bid = blockIdx.x;
  int swz = (bid & 7) * 2048 + (bid >> 3);
  int b = swz;
  size_t m0 = (size_t)swz * 128;
  int tid = threadIdx.x;
  int wave = tid >> 6, lane = tid & 63;
  int wr = wave >> 1, wc = wave & 1;
  int r = tid >> 1, h = tid & 1;
  int la = lane & 15, lkq = lane >> 4;
  int sl = ((lkq ^ ((la >> 1) & 3))) * 8;   // swizzled A k-slot (ABF=1)

  if (ABF) {
    // stage B from prebuilt WvT bf16 [128][128] (L2-resident): 8x b128 per thread
#pragma unroll
    for (int q = 0; q < 8; ++q) {
      bf16x8 v = *(const bf16x8*)(WvT + (size_t)r * 128 + h * 64 + q * 8);
      *(bf16x8*)(Bs + r * 136 + h * 64 + q * 8) = v;
    }
  } else {
#pragma unroll
    for (int q = 0; q < 16; ++q) {
      int flat = q * 256 + tid;
      int k = flat >> 5;
      int n4 = (flat & 31) * 4;
      float4 v = *(const float4*)(Wv + (size_t)k * 128 + n4);
      Bs[(n4 + 0) * 136 + k] = f2bf(v.x);
      Bs[(n4 + 1) * 136 + k] = f2bf(v.y);
      Bs[(n4 + 2) * 136 + k] = f2bf(v.z);
      Bs[(n4 + 3) * 136 + k] = f2bf(v.w);
    }
  }

  // ABF=1 A staging: physical chunk p -> tile row tr = p>>2 = (n,a), swizzled slot
  const unsigned short *ap0 = nullptr, *ap1 = nullptr;
  int ldsA0 = wave * 1024, ldsA1 = ldsA0 + 512;
  if (ABF) {
    int p0 = wave * 128 + lane;
    int tr0 = p0 >> 2, ds0 = (p0 & 3) ^ ((tr0 >> 1) & 3);
    int p1 = p0 + 64;
    int tr1 = p1 >> 2, ds1 = (p1 & 3) ^ ((tr1 >> 1) & 3);
    ap0 = Abf + ((size_t)b * 8 + (tr0 >> 4)) * 2304 + 128 + (tr0 & 15) * 128 + ds0 * 8;
    ap1 = Abf + ((size_t)b * 8 + (tr1 >> 4)) * 2304 + 128 + (tr1 & 15) * 128 + ds1 * 8;
    __builtin_amdgcn_global_load_lds(
        (const __attribute__((address_space(1))) void*)(ap0),
        (__attribute__((address_space(3))) void*)(As + ldsA0), 16, 0, 0);
    __builtin_amdgcn_global_load_lds(
        (const __attribute__((address_space(1))) void*)(ap1),
        (__attribute__((address_space(3))) void*)(As + ldsA1), 16, 0, 0);
  }

  f32x4 acc[4][4];
#pragma unroll
  for (int i = 0; i < 4; ++i)
#pragma unroll
    for (int j = 0; j < 4; ++j) acc[i][j] = (f32x4)(0.f);

  if (ABF) __syncthreads();  // covers B ds_writes + A gload(0)

  int cur = 0;
  for (int ks = 0; ks < 4; ++ks) {
    int k0 = ks * 32;
    if (ABF) {
      if (ks < 3) {
        __builtin_amdgcn_global_load_lds(
            (const __attribute__((address_space(1))) void*)(ap0 + k0 + 32),
            (__attribute__((address_space(3))) void*)(As + (cur ^ 1) * 4096 + ldsA0), 16, 0, 0);
        __builtin_amdgcn_global_load_lds(
            (const __attribute__((address_space(1))) void*)(ap1 + k0 + 32),
            (__attribute__((address_space(3))) void*)(As + (cur ^ 1) * 4096 + ldsA1), 16, 0, 0);
      }
    } else {
      const float* ap = sf + (m0 + r) * 128 + k0 + h * 16;
      float4 v0 = *(const float4*)(ap);
      float4 v1 = *(const float4*)(ap + 4);
      float4 v2 = *(const float4*)(ap + 8);
      float4 v3 = *(const float4*)(ap + 12);
      ushort4 p0 = make_ushort4(f2bf(v0.x), f2bf(v0.y), f2bf(v0.z), f2bf(v0.w));
      ushort4 p1 = make_ushort4(f2bf(v1.x), f2bf(v1.y), f2bf(v1.z), f2bf(v1.w));
      ushort4 p2 = make_ushort4(f2bf(v2.x), f2bf(v2.y), f2bf(v2.z), f2bf(v2.w));
      ushort4 p3 = make_ushort4(f2bf(v3.x), f2bf(v3.y), f2bf(v3.z), f2bf(v3.w));
      *(ushort4*)(As + r * 40 + h * 16)      = p0;
      *(ushort4*)(As + r * 40 + h * 16 + 4)  = p1;
      *(ushort4*)(As + r * 40 + h * 16 + 8)  = p2;
      *(ushort4*)(As + r * 40 + h * 16 + 12) = p3;
      __syncthreads();
    }
    const unsigned short* aL = ABF ? (As + cur * 4096) : As;
    bf16x8 af[4], bfr[4];
#pragma unroll
    for (int mi = 0; mi < 4; ++mi) {
      int rowl = wr * 64 + mi * 16 + la;
      af[mi] = ABF ? *(const bf16x8*)(aL + rowl * 32 + sl)
                   : *(const bf16x8*)(aL + rowl * 40 + lkq * 8);
    }
#pragma unroll
    for (int ni = 0; ni < 4; ++ni)
      bfr[ni] = *(const bf16x8*)(Bs + (wc * 64 + ni * 16 + la) * 136 + k0 + lkq * 8);
#pragma unroll
    for (int mi = 0; mi < 4; ++mi)
#pragma unroll
      for (int ni = 0; ni < 4; ++ni)
        acc[mi][ni] = __builtin_amdgcn_mfma_f32_16x16x32_bf16(af[mi], bfr[ni], acc[mi][ni], 0, 0, 0);
    __syncthreads();
    cur ^= 1;
  }

  // epilogue: vm write + weighted partials over mi (n = wr*4+mi)
  float w4[4];
#pragma unroll
  for (int mi = 0; mi < 4; ++mi) w4[mi] = wts[(size_t)b * 8 + wr * 4 + mi];
  float pacc[4][4];  // [ni][j]
#pragma unroll
  for (int ni = 0; ni < 4; ++ni)
#pragma unroll
    for (int j = 0; j < 4; ++j) pacc[ni][j] = 0.f;
#pragma unroll
  for (int mi = 0; mi < 4; ++mi) {
#pragma unroll
    for (int ni = 0; ni < 4; ++ni) {
      int colg = wc * 64 + ni * 16 + la;
      float bb = bv[colg];
#pragma unroll
      for (int j = 0; j < 4; ++j) {
        size_t rowg = m0 + wr * 64 + mi * 16 + lkq * 4 + j;
        float v = acc[mi][ni][j] + bb;
        vm[rowg * 128 + colg] = v;
        pacc[ni][j] = fmaf(w4[mi], v, pacc[ni][j]);
      }
    }
  }
  // cross-wave (wr) reduce into attL[a][col], a = lkq*4+j
  if (wr == 0) {
#pragma unroll
    for (int ni = 0; ni < 4; ++ni)
#pragma unroll
      for (int j = 0; j < 4; ++j)
        attL[(lkq * 4 + j) * 132 + wc * 64 + ni * 16 + la] = pacc[ni][j];
  }
  __syncthreads();
  if (wr == 1) {
#pragma unroll
    for (int ni = 0; ni < 4; ++ni)
#pragma unroll
      for (int j = 0; j < 4; ++j)
        attL[(lkq * 4 + j) * 132 + wc * 64 + ni * 16 + la] += pacc[ni][j];
  }
  __syncthreads();
  // write attended (2048 f32) + q1 (16)
#pragma unroll
  for (int i = 0; i < 2; ++i) {
    int fidx = tid + i * 256;
    int a = fidx >> 5, c = (fidx & 31) * 4;
    f32x4 vv = *(const f32x4*)(attL + a * 132 + c);
    *(f32x4*)(att + (size_t)b * 2048 + a * 128 + c) = vv;
  }
  for (int j = wave; j < 16; j += 4) {
    float p = task[(size_t)b * 1024 + lane] * attL[j * 132 + lane]
            + task[(size_t)b * 1024 + 64 + lane] * attL[j * 132 + 64 + lane];
    p = wave_sum(p);
    if (lane == 0) q1[(size_t)b * 16 + j] = p;
  }
}

extern "C" void kernel_launch(void* const* d_in, const int* in_sizes, int n_in,
                              void* d_out, int out_size, void* d_ws, size_t ws_size,
                              hipStream_t stream) {
  const float* basis = (const float*)d_in[0];
  const float* sf    = (const float*)d_in[1];
  const float* task  = (const float*)d_in[2];
  const float* mask  = (const float*)d_in[3];
  const float* Wq    = (const float*)d_in[4];
  const float* Wk    = (const float*)d_in[5];
  const float* bk    = (const float*)d_in[6];
  const float* Wv    = (const float*)d_in[7];
  const float* bv    = (const float*)d_in[8];

  float* out  = (float*)d_out;
  float* q1   = out;
  float* att  = out + OFF_ATT;
  float* logi = out + OFF_LOG;
  float* wts  = out + OFF_W;
  float* km   = out + OFF_KM;
  float* vm   = out + OFF_VM;
  float* simo = out + OFF_SIM;

  // d_ws layout (preferred path): Abf | WkT | WqT | WvT | query | invn = ~634MB.
  constexpr size_t WS_NEED = 603979776ull + 1769472ull + 1769472ull + 32768ull +
                             25165824ull + 524288ull;
  bool usews = ws_size >= WS_NEED;

  unsigned short *Abf, *WkT, *WqT, *WvT = nullptr;
  float *query, *invn;
  if (usews) {
    unsigned char* ws = (unsigned char*)d_ws;
    Abf   = (unsigned short*)ws;
    WkT   = (unsigned short*)(ws + 603979776ull);
    WqT   = (unsigned short*)(ws + 605749248ull);
    WvT   = (unsigned short*)(ws + 607518720ull);
    query = (float*)(ws + 607551488ull);
    invn  = (float*)(ws + 632717312ull);
  } else {
    query = att;                                     // 6,291,456 f32
    invn  = att + 6291456;                           //   131,072 f32
    WkT   = (unsigned short*)(att + 6422528);        //   884,736 bf16
    WqT   = WkT + 884736;                            //   884,736 bf16
    Abf   = (unsigned short*)vm;                     // 301,989,888 bf16
  }

  norm_kernel<<<32768, 256, 0, stream>>>(task, invn, simo);
  wprep_t<<<216, 256, 0, stream>>>(Wk, WkT, 2304, 384);
  wprep_t<<<216, 256, 0, stream>>>(Wq, WqT, 2304, 384);
  if (usews) wprep_t<<<4, 256, 0, stream>>>(Wv, WvT, 128, 128);
  abuild_sim<<<16384, 576, 0, stream>>>(basis, sf, task, invn, Abf, simo);
  // keys: M=131072, N=384 (3 n-tiles), K=2304; bias + mask
  qk_gemm<0><<<3072, 256, 0, stream>>>(Abf, WkT, bk, mask, km);
  // query: M=16384 (Abf rows stride 8), N=384, K=2304
  qk_gemm<1><<<384, 256, 0, stream>>>(Abf, WqT, nullptr, nullptr, query);
  attn_kernel4<<<4096, 256, 0, stream>>>(query, km, logi, wts);
  // values GEMM + fused attend/q1: M=2,097,152, N=128, K=128
  if (usews)
    v_gemm_attend<1><<<16384, 256, 0, stream>>>(sf, Abf, Wv, WvT, bv, wts, task, vm, att, q1);
  else
    v_gemm_attend<0><<<16384, 256, 0, stream>>>(sf, Abf, Wv, WvT, bv, wts, task, vm, att, q1);
}